// Round 1
// baseline (90.324 us; speedup 1.0000x reference)
//
#include <hip/hip_runtime.h>

// Problem constants (from setup_inputs): B=4, N=100000, M=64
#define B_IMGS 4
#define N_PROP 100000
#define M_GT   64

// Output layout (flat f32): decoded[B*N*4] | targets[B*N*4] | matches[B*N]

__global__ __launch_bounds__(256) void roihead_kernel(
    const float* __restrict__ proposals,  // [B,N,4]
    const float* __restrict__ gt,         // [B,M,4]
    const float* __restrict__ deltas,     // [B,N,4]
    float* __restrict__ out)
{
    __shared__ float4 g_s[M_GT];
    __shared__ float  ga_s[M_GT];

    const int b   = blockIdx.y;
    const int tid = threadIdx.x;

    // Stage gt boxes + areas for this image in LDS (broadcast reads later).
    if (tid < M_GT) {
        float4 g = reinterpret_cast<const float4*>(gt)[b * M_GT + tid];
        g_s[tid]  = g;
        ga_s[tid] = (g.z - g.x) * (g.w - g.y);  // matches numpy op order
    }
    __syncthreads();

    const int n = blockIdx.x * blockDim.x + tid;
    if (n >= N_PROP) return;

    const long pi = (long)b * N_PROP + n;
    const float4 p = reinterpret_cast<const float4*>(proposals)[pi];

    // ---- Matcher: IoU argmax over 64 gts. MUST be bit-exact vs numpy ----
    float best_v = -1.0f;
    int   best_i = 0;
    {
#pragma clang fp contract(off)
        const float area_p = (p.z - p.x) * (p.w - p.y);
        for (int m = 0; m < M_GT; ++m) {
            const float4 g = g_s[m];
            const float ltx = fmaxf(g.x, p.x);
            const float lty = fmaxf(g.y, p.y);
            const float rbx = fminf(g.z, p.z);
            const float rby = fminf(g.w, p.w);
            const float wx  = fmaxf(rbx - ltx, 0.0f);
            const float wy  = fmaxf(rby - lty, 0.0f);
            const float inter = wx * wy;
            // numpy: inter / (area_g + area_p - inter), IEEE f32 division
            const float iou = inter / ((ga_s[m] + area_p) - inter);
            if (iou > best_v) { best_v = iou; best_i = m; }  // first max wins
        }
    }

    int match = best_i;
    if (best_v < 0.5f) match = -1;                    // BELOW_LOW (BG_THRESH)
    else if (best_v < 0.5f) match = -2;               // BETWEEN (dead: FG==BG)

    // ---- BoxCoder.encode against matched (clamped) gt ----
    const float4 mg = g_s[match > 0 ? match : 0];
    const float aw = p.z - p.x;
    const float ah = p.w - p.y;
    const float ax = p.x + 0.5f * aw;
    const float ay = p.y + 0.5f * ah;
    const float gw = fmaxf(mg.z - mg.x, 1.0f);
    const float gh = fmaxf(mg.w - mg.y, 1.0f);
    const float gx = mg.x + 0.5f * gw;
    const float gy = mg.y + 0.5f * gh;

    float4 tgt;
    tgt.x = ((gx - ax) / aw) / 0.1f;
    tgt.y = ((gy - ay) / ah) / 0.1f;
    tgt.z = logf(gw / aw) / 0.2f;
    tgt.w = logf(gh / ah) / 0.2f;

    // ---- BoxCoder.decode for predicted deltas ----
    const float4 d = reinterpret_cast<const float4*>(deltas)[pi];
    const float sx = d.x * 0.1f;
    const float sy = d.y * 0.1f;
    const float sw = d.z * 0.2f;
    const float sh = d.w * 0.2f;
    const float cx = ax + sx * aw;
    const float cy = ay + sy * ah;
    const float w2 = expf(sw) * aw;
    const float h2 = expf(sh) * ah;

    float4 dec;
    dec.x = cx - 0.5f * w2;
    dec.y = cy - 0.5f * h2;
    dec.z = cx + 0.5f * w2;
    dec.w = cy + 0.5f * h2;

    // ---- Writes (all coalesced float4 except matches) ----
    float4* out4 = reinterpret_cast<float4*>(out);
    out4[pi] = dec;                                   // decoded
    out4[(long)B_IMGS * N_PROP + pi] = tgt;           // targets
    out[(long)2 * B_IMGS * N_PROP * 4 + pi] = (float)match;  // matches as f32
}

extern "C" void kernel_launch(void* const* d_in, const int* in_sizes, int n_in,
                              void* d_out, int out_size, void* d_ws, size_t ws_size,
                              hipStream_t stream) {
    const float* proposals = (const float*)d_in[0];
    const float* gt        = (const float*)d_in[1];
    const float* deltas    = (const float*)d_in[2];
    float* out = (float*)d_out;

    dim3 block(256);
    dim3 grid((N_PROP + 255) / 256, B_IMGS);
    roihead_kernel<<<grid, block, 0, stream>>>(proposals, gt, deltas, out);
}